// Round 17
// baseline (2910.189 us; speedup 1.0000x reference)
//
#include <hip/hip_runtime.h>
#include <hip/hip_bf16.h>
#include <stdint.h>

typedef __attribute__((ext_vector_type(8))) short short8;
typedef __attribute__((ext_vector_type(4))) float f32x4;
typedef __attribute__((ext_vector_type(4))) unsigned int u32x4;
typedef __attribute__((ext_vector_type(2))) unsigned int u32x2;

__device__ __forceinline__ unsigned short f2bf(float x) {
  unsigned int u = __builtin_bit_cast(unsigned int, x);
  u += 0x7FFFu + ((u >> 16) & 1u);           // round-to-nearest-even
  return (unsigned short)(u >> 16);
}
__device__ __forceinline__ float bf2f(unsigned short u) {
  unsigned int v = ((unsigned int)u) << 16;
  return __builtin_bit_cast(float, v);
}
__device__ __forceinline__ unsigned int pk2(float a, float b) {
  return (unsigned int)f2bf(a) | ((unsigned int)f2bf(b) << 16);
}
__device__ __forceinline__ float sigm(float x) {
  return __builtin_amdgcn_rcpf(1.0f + __builtin_amdgcn_exp2f(-1.44269504f * x));
}
__device__ __forceinline__ float tanh_(float x) {
  return 2.0f * __builtin_amdgcn_rcpf(1.0f + __builtin_amdgcn_exp2f(-2.88539008f * x)) - 1.0f;
}
__device__ __forceinline__ f32x4 mfma16(short8 a, short8 b, f32x4 c) {
  return __builtin_amdgcn_mfma_f32_16x16x32_bf16(a, b, c, 0, 0, 0);
}
__device__ __forceinline__ short8 bc(u32x4 v) { return __builtin_bit_cast(short8, v); }

// ---------------------------------------------------------------------------
// prep: bf16 transposed weight images, fused bias, init 4-domain h ring.
// Gate order: 0=f, 1=i, 2=g, 3=o.
// WxT: [2048 n][512 k]   WhT: [32 wgl][64 j][512 k]  (j = gate*16 + hc_local)
// h ring: 4 domains x 4 slots x [16 rows][512 cols] bf16 (domain d = batch
// rows 16d..16d+15). Per domain: slot 0 = h_0 = +0.0 (fresh); slots 1..3 =
// 0x8000 poison (bf16 -0.0, never produced: producers cleanse).
// ---------------------------------------------------------------------------
__global__ void lstm_prep(
    const float* __restrict__ Wif, const float* __restrict__ Wii,
    const float* __restrict__ Wig, const float* __restrict__ Wio,
    const float* __restrict__ Whf, const float* __restrict__ Whi,
    const float* __restrict__ Whg, const float* __restrict__ Who,
    const float* __restrict__ bif, const float* __restrict__ bhf,
    const float* __restrict__ bii, const float* __restrict__ bhi,
    const float* __restrict__ big, const float* __restrict__ bhg,
    const float* __restrict__ bio, const float* __restrict__ bho,
    unsigned short* __restrict__ WxT, unsigned short* __restrict__ WhT,
    float* __restrict__ bias, unsigned short* __restrict__ hring)
{
  const long NWX = 2048L * 512, NWH = 32L * 64 * 512;
  const long NR = 4L * 4 * 16 * 512;           // ring: 131072 ushorts
  long total = NWX + NWH + 2048 + NR;
  for (long i = (long)blockIdx.x * blockDim.x + threadIdx.x; i < total;
       i += (long)gridDim.x * blockDim.x) {
    if (i < NWX) {
      int n = (int)(i >> 9), k = (int)(i & 511);
      int g = n >> 9, hc = n & 511;
      const float* W = (g == 0) ? Wif : (g == 1) ? Wii : (g == 2) ? Wig : Wio;
      WxT[i] = f2bf(W[k * 512 + hc]);
    } else if (i < NWX + NWH) {
      long r = i - NWX;
      int wg = (int)(r >> 15); int rest = (int)(r & 32767);
      int j = rest >> 9, k = rest & 511;
      int g = j >> 4, hc = wg * 16 + (j & 15);
      const float* W = (g == 0) ? Whf : (g == 1) ? Whi : (g == 2) ? Whg : Who;
      WhT[r] = f2bf(W[k * 512 + hc]);
    } else if (i < NWX + NWH + 2048) {
      int n = (int)(i - NWX - NWH);
      int g = n >> 9, hc = n & 511;
      const float* bi = (g == 0) ? bif : (g == 1) ? bii : (g == 2) ? big : bio;
      const float* bh = (g == 0) ? bhf : (g == 1) ? bhi : (g == 2) ? bhg : bho;
      bias[n] = bi[hc] + bh[hc];
    } else {
      long r = i - NWX - NWH - 2048;
      long rr = r & 32767;                     // within-domain index
      hring[r] = (rr < 8192) ? (unsigned short)0 : (unsigned short)0x8000u;
    }
  }
}

// ---------------------------------------------------------------------------
// x-projection GEMM: (B*T, 512) @ (512, 2048) + bias -> bf16, written in the
// recurrent kernel's per-lane-packed layout (4-domain, gate-per-wave):
//   dst = ((((t*128 + dd*32 + wgl)*4 + gate)*64 + (chi*16+lcol))*4 + cii
// where b = dd*16 + rloc, chi = rloc>>2, cii = rloc&3, lcol = hc&15.
// ---------------------------------------------------------------------------
#define GP 56  // LDS row stride (elems): 112B, 16B-aligned, 2-way banks

__global__ __launch_bounds__(256) void lstm_xproj(
    const float* __restrict__ x, const unsigned short* __restrict__ WxT,
    const float* __restrict__ bias, unsigned short* __restrict__ xp)
{
  __shared__ unsigned short As[128 * GP];
  __shared__ unsigned short Bs[128 * GP];
  int bid = blockIdx.x;
  int mt = bid & 511, nt = bid >> 9;          // 512 m-tiles, 16 n-tiles
  int m0 = mt << 7, n0 = nt << 7;
  int tid = threadIdx.x, lane = tid & 63, w = tid >> 6;
  int wm = w >> 1, wn = w & 1;
  int l15 = lane & 15, hi4 = lane >> 4;

  f32x4 acc[4][4] = {};
  int srow = tid >> 1, skq = (tid & 1) << 4;  // each thread: 1 row, 16 k
  const float* xa = x + (size_t)(m0 + srow) * 512 + skq;
  const unsigned short* bsrc = WxT + (size_t)(n0 + srow) * 512 + skq;
  unsigned short* adst = As + srow * GP + skq;
  unsigned short* bdst = Bs + srow * GP + skq;

  for (int kt = 0; kt < 16; ++kt) {
    f32x4 a0 = *(const f32x4*)(xa + kt * 32);
    f32x4 a1 = *(const f32x4*)(xa + kt * 32 + 4);
    f32x4 a2 = *(const f32x4*)(xa + kt * 32 + 8);
    f32x4 a3 = *(const f32x4*)(xa + kt * 32 + 12);
    u32x4 wv0 = *(const u32x4*)(bsrc + kt * 32);
    u32x4 wv1 = *(const u32x4*)(bsrc + kt * 32 + 8);
    u32x4 p0, p1;
    p0[0] = pk2(a0[0], a0[1]); p0[1] = pk2(a0[2], a0[3]);
    p0[2] = pk2(a1[0], a1[1]); p0[3] = pk2(a1[2], a1[3]);
    p1[0] = pk2(a2[0], a2[1]); p1[1] = pk2(a2[2], a2[3]);
    p1[2] = pk2(a3[0], a3[1]); p1[3] = pk2(a3[2], a3[3]);
    *(u32x4*)adst = p0;  *(u32x4*)(adst + 8) = p1;
    *(u32x4*)bdst = wv0; *(u32x4*)(bdst + 8) = wv1;
    __syncthreads();
    short8 af[4], bfr[4];
    #pragma unroll
    for (int mb = 0; mb < 4; ++mb)
      af[mb] = *(const short8*)(As + (wm * 64 + mb * 16 + l15) * GP + hi4 * 8);
    #pragma unroll
    for (int nb = 0; nb < 4; ++nb)
      bfr[nb] = *(const short8*)(Bs + (wn * 64 + nb * 16 + l15) * GP + hi4 * 8);
    #pragma unroll
    for (int mb = 0; mb < 4; ++mb)
      #pragma unroll
      for (int nb = 0; nb < 4; ++nb)
        acc[mb][nb] = mfma16(af[mb], bfr[nb], acc[mb][nb]);
    __syncthreads();
  }
  // epilogue: +bias, bf16, scatter into packed consumer layout
  #pragma unroll
  for (int nb = 0; nb < 4; ++nb) {
    int n = n0 + wn * 64 + nb * 16 + l15;
    int gate = n >> 9, hc = n & 511, wgc = hc >> 4, lcol = hc & 15;
    float bv = bias[n];
    #pragma unroll
    for (int mb = 0; mb < 4; ++mb) {
      int mbase = m0 + wm * 64 + mb * 16 + hi4 * 4;
      #pragma unroll
      for (int i = 0; i < 4; ++i) {
        int m = mbase + i;
        int tt = m & 1023, bb = m >> 10;
        int ddc = bb >> 4, rloc = bb & 15;
        int chi = rloc >> 2, cii = rloc & 3;
        size_t dst = ((((size_t)tt * 128 + ddc * 32 + wgc) * 4 + gate) * 64 +
                      (size_t)(chi * 16 + lcol)) * 4 + cii;
        xp[dst] = f2bf(acc[mb][nb][i] + bv);
      }
    }
  }
}

// ---------------------------------------------------------------------------
// recurrence: 4 independent batch domains x 32 WGs = 128 WGs. R11 protocol
// with the top-of-step drain path cleaned:
//  - publishers remapped to (tid&1)==0 (32/wave) so EVERY wave's gb issue
//    follows its own publish in program order;
//  - the single gb snapshot is issued AFTER the publish store (fresh at the
//    next check; no duplicated traffic -- R14's mistake avoided);
//  - re-poison issued AFTER the poll completes (ack rides under MFMA+combine,
//    drained free at next top; commit-before-reuse chain still holds: a
//    consumer seeing h_{t+1} implies our earlier-committed re-poison).
// ---------------------------------------------------------------------------
#define AWAIT(N) do { \
  asm volatile("s_waitcnt vmcnt(" #N ")" ::: "memory"); \
  __builtin_amdgcn_sched_barrier(0); } while (0)

#define PLD1(dst, vof, sb) \
  asm volatile("global_load_dwordx4 %0, %1, %2 sc0 sc1" \
               : "=v"(dst) : "v"(vof), "s"(sb))

#define XLD2(dst, a64) \
  asm volatile("global_load_dwordx2 %0, %1, off" : "=v"(dst) : "v"(a64))

__global__ __launch_bounds__(256, 1) void lstm_rec(
    const unsigned short* __restrict__ xp, const unsigned short* __restrict__ WhT,
    unsigned short* __restrict__ hring, float* __restrict__ out)
{
  __shared__ unsigned short hA[8192];    // 16 KB staged h (XOR-swizzled)
  __shared__ float pre[4][16][17];       // 4.4 KB preact exchange

  int wgG = blockIdx.x;
  int dd = wgG >> 5, wgl = wgG & 31;
  int tid = threadIdx.x, lane = tid & 63, g = tid >> 6;   // wave = gate
  int l15 = lane & 15, hi4 = lane >> 4;

  // Wh fragments for this wave's gate: 16 x short8 = 64 VGPR
  short8 bw[16];
  {
    const unsigned short* wsrc =
        WhT + ((size_t)wgl * 64 + g * 16 + l15) * 512 + hi4 * 8;
    #pragma unroll
    for (int kk = 0; kk < 16; ++kk)
      bw[kk] = *(const short8*)(wsrc + kk * 32);
  }

  // poll voffsets + swizzled LDS bytes: 4 granules/thread (16B each)
  unsigned int voff[4], lbyt[4];
  #pragma unroll
  for (int k = 0; k < 4; ++k) {
    int gid = k * 256 + tid;         // granule id 0..1023
    int byt = gid * 16;
    int row = gid >> 6;              // 16 rows, 64 granules/row
    voff[k] = (unsigned)byt;
    lbyt[k] = (unsigned)(byt ^ ((row & 7) << 4));
  }
  // own-column granules (gcol = tid&63): excluded from poll
  int gcol = tid & 63;
  unsigned own = (gcol == wgl * 2 || gcol == wgl * 2 + 1) ? 0xFu : 0x0u;

  // combine workers: (tid&1)==0 -> 32 publishers in EVERY wave
  const int active = ((tid & 1) == 0);
  const int idx = tid >> 1;              // 0..127
  const int r = idx >> 3;                // row 0..15
  const int cq = (idx & 7) * 2;          // first of 2 local cols
  float cst[2] = {0.f, 0.f};
  unsigned int vpub = (unsigned)(r * 1024 + (wgl * 16 + cq) * 2);
  unsigned int lown = (unsigned)((r * 1024 + (wgl * 16 + cq) * 2)
                                 ^ ((r & 7) << 4));

  // per-lane 64-bit xp address (this wave's 8B/lane packet for step t)
  unsigned long long xaddr = (unsigned long long)(uintptr_t)(
      xp + ((size_t)(wgG * 4 + g) * 64 + lane) * 4);

  u32x2 pc, pn;
  XLD2(pc, xaddr);

  const size_t dbase = (size_t)dd * 32768;   // domain base (elems)

  u32x4 gb[4];
  // prologue: first-round polls for slot 0 (fresh from prep)
  {
    const unsigned short* hb = hring + dbase;
    #pragma unroll
    for (int k = 0; k < 4; ++k) PLD1(gb[k], voff[k], hb);
  }

  for (int t = 0; t < 1024; ++t) {
    const unsigned short* hb = hring + dbase + ((size_t)(t & 3) << 13);
    // ---- drain last step's gb/pn/publish/re-poison; check snapshot ----
    unsigned m = (t == 0) ? 0xFu : (0xFu & ~own);
    {
      AWAIT(0);
      unsigned nm = 0;
      #pragma unroll
      for (int k = 0; k < 4; ++k) {
        if ((m >> k) & 1u) {
          u32x4 v = gb[k];
          bool clean = (v[0] != 0x80008000u) && (v[1] != 0x80008000u) &&
                       (v[2] != 0x80008000u) && (v[3] != 0x80008000u);
          if (clean)
            *(u32x4*)((char*)hA + lbyt[k]) = v;   // stage now
          else
            nm |= (1u << k);
        }
      }
      m = nm;
      int spins = 0;
      while (m != 0u) {                  // re-poll dirty granules
        #pragma unroll
        for (int k = 0; k < 4; ++k)
          if ((m >> k) & 1u) PLD1(gb[k], voff[k], hb);
        AWAIT(0);
        unsigned n2 = 0;
        #pragma unroll
        for (int k = 0; k < 4; ++k) {
          if ((m >> k) & 1u) {
            u32x4 v = gb[k];
            bool clean = (v[0] != 0x80008000u) && (v[1] != 0x80008000u) &&
                         (v[2] != 0x80008000u) && (v[3] != 0x80008000u);
            if (clean)
              *(u32x4*)((char*)hA + lbyt[k]) = v;
            else
              n2 |= (1u << k);
          }
        }
        m = n2;
        if (++spins > (1 << 15)) break;   // bounded: fail visibly, never hang
      }
    }
    // ---- re-poison slot (t-2): AFTER poll, ack rides to next top ----
    if (t >= 2 && active) {
      const unsigned short* hp = hring + dbase + ((size_t)((t - 2) & 3) << 13);
      unsigned int pv = 0x80008000u;
      asm volatile("global_store_dword %0, %1, %2 sc0 sc1"
                   :: "v"(vpub), "v"(pv), "s"(hp) : "memory");
    }
    __syncthreads();                // B1: staged h_t complete in LDS

    // ---- acc init from prefetched xp ----
    f32x4 acc;
    #pragma unroll
    for (int i = 0; i < 4; ++i) {
      unsigned int dw = pc[i >> 1];
      unsigned short us = (i & 1) ? (unsigned short)(dw >> 16)
                                  : (unsigned short)(dw & 0xFFFFu);
      acc[i] = bf2f(us);
    }
    if (t < 1023) xaddr += 262144ULL;   // uniform step to next t's packet
    XLD2(pn, xaddr);

    // ---- MFMA: a-frags from swizzled LDS, b-frags from regs ----
    #pragma unroll
    for (int kk = 0; kk < 16; ++kk) {
      int b0 = (l15 * 1024 + kk * 64 + hi4 * 16) ^ ((l15 & 7) << 4);
      short8 a0 = *(const short8*)((const char*)hA + b0);
      acc = mfma16(a0, bw[kk], acc);
    }
    // ---- preact dump ----
    #pragma unroll
    for (int i = 0; i < 4; ++i)
      pre[g][hi4 * 4 + i][l15] = acc[i];
    __syncthreads();                // B2

    // ---- combine (active lanes): row r, local cols cq..cq+1; publish ----
    if (active) {
      float hv[2];
      #pragma unroll
      for (int i = 0; i < 2; ++i) {
        float fg = sigm(pre[0][r][cq + i]);
        float ig = sigm(pre[1][r][cq + i]);
        float gg = tanh_(pre[2][r][cq + i]);
        float og = sigm(pre[3][r][cq + i]);
        float c = fg * cst[i] + ig * gg;
        cst[i] = c;
        hv[i] = og * tanh_(c);
      }
      if (t < 1023) {
        unsigned int u0 = f2bf(hv[0]), u1 = f2bf(hv[1]);
        if (u0 == 0x8000u) u0 = 0;    // cleanse -0.0 (poison)
        if (u1 == 0x8000u) u1 = 0;
        unsigned int pk = u0 | (u1 << 16);
        const unsigned short* hbn =
            hring + dbase + ((size_t)((t + 1) & 3) << 13);
        asm volatile("global_store_dword %0, %1, %2 sc0 sc1"
                     :: "v"(vpub), "v"(pk), "s"(hbn) : "memory");
        // own slice direct to LDS for next step (skips the global RT)
        *(unsigned int*)((char*)hA + lown) = pk;
      } else {
        int b = dd * 16 + r, col = wgl * 16 + cq;
        out[(size_t)b * 512 + col] = hv[0];
        out[(size_t)b * 512 + col + 1] = hv[1];
        out[32768 + (size_t)b * 512 + col] = cst[0];
        out[32768 + (size_t)b * 512 + col + 1] = cst[1];
      }
    }
    // ---- gb snapshot for slot t+1: issued AFTER the publish store ----
    if (t < 1023) {
      const unsigned short* hbn =
          hring + dbase + ((size_t)((t + 1) & 3) << 13);
      #pragma unroll
      for (int k = 0; k < 4; ++k)
        if (!((own >> k) & 1u)) PLD1(gb[k], voff[k], hbn);
    }
    pc = pn;
  }
}

// ---------------------------------------------------------------------------
extern "C" void kernel_launch(void* const* d_in, const int* in_sizes, int n_in,
                              void* d_out, int out_size, void* d_ws, size_t ws_size,
                              hipStream_t stream) {
  const float* x   = (const float*)d_in[0];
  const float* Wii = (const float*)d_in[1];
  const float* Whi = (const float*)d_in[2];
  const float* Wif = (const float*)d_in[3];
  const float* Whf = (const float*)d_in[4];
  const float* Wig = (const float*)d_in[5];
  const float* Whg = (const float*)d_in[6];
  const float* Wio = (const float*)d_in[7];
  const float* Who = (const float*)d_in[8];
  const float* bii = (const float*)d_in[9];
  const float* bhi = (const float*)d_in[10];
  const float* bif = (const float*)d_in[11];
  const float* bhf = (const float*)d_in[12];
  const float* big = (const float*)d_in[13];
  const float* bhg = (const float*)d_in[14];
  const float* bio = (const float*)d_in[15];
  const float* bho = (const float*)d_in[16];

  char* ws = (char*)d_ws;
  size_t off = 0;
  auto alloc = [&](size_t bytes) {
    size_t p = off; off = (off + bytes + 255) & ~(size_t)255; return p;
  };
  unsigned short* WxT  = (unsigned short*)(ws + alloc(2048UL * 512 * 2));
  unsigned short* WhT  = (unsigned short*)(ws + alloc(32UL * 64 * 512 * 2));
  float*          bias = (float*)        (ws + alloc(2048UL * 4));
  unsigned short* hring= (unsigned short*)(ws + alloc(4UL * 4 * 16 * 512 * 2));
  unsigned short* xpb  = (unsigned short*)(ws + alloc(1024UL * 64 * 2048 * 2));
  if (off > ws_size) return;  // insufficient workspace -> fail visibly

  lstm_prep<<<2048, 256, 0, stream>>>(Wif, Wii, Wig, Wio, Whf, Whi, Whg, Who,
                                      bif, bhf, bii, bhi, big, bhg, bio, bho,
                                      WxT, WhT, bias, hring);
  lstm_xproj<<<8192, 256, 0, stream>>>(x, WxT, bias, xpb);
  lstm_rec<<<128, 256, 0, stream>>>(xpb, WhT, hring, (float*)d_out);
}

// Round 18
// 2803.687 us; speedup vs baseline: 1.0380x; 1.0380x over previous
//
#include <hip/hip_runtime.h>
#include <hip/hip_bf16.h>
#include <stdint.h>

typedef __attribute__((ext_vector_type(8))) short short8;
typedef __attribute__((ext_vector_type(4))) float f32x4;
typedef __attribute__((ext_vector_type(4))) unsigned int u32x4;
typedef __attribute__((ext_vector_type(2))) unsigned int u32x2;

__device__ __forceinline__ unsigned short f2bf(float x) {
  unsigned int u = __builtin_bit_cast(unsigned int, x);
  u += 0x7FFFu + ((u >> 16) & 1u);           // round-to-nearest-even
  return (unsigned short)(u >> 16);
}
__device__ __forceinline__ float bf2f(unsigned short u) {
  unsigned int v = ((unsigned int)u) << 16;
  return __builtin_bit_cast(float, v);
}
__device__ __forceinline__ unsigned int pk2(float a, float b) {
  return (unsigned int)f2bf(a) | ((unsigned int)f2bf(b) << 16);
}
__device__ __forceinline__ float sigm(float x) {
  return __builtin_amdgcn_rcpf(1.0f + __builtin_amdgcn_exp2f(-1.44269504f * x));
}
__device__ __forceinline__ float tanh_(float x) {
  return 2.0f * __builtin_amdgcn_rcpf(1.0f + __builtin_amdgcn_exp2f(-2.88539008f * x)) - 1.0f;
}
__device__ __forceinline__ f32x4 mfma16(short8 a, short8 b, f32x4 c) {
  return __builtin_amdgcn_mfma_f32_16x16x32_bf16(a, b, c, 0, 0, 0);
}
__device__ __forceinline__ short8 bc(u32x4 v) { return __builtin_bit_cast(short8, v); }

// ---------------------------------------------------------------------------
// prep: bf16 transposed weight images, fused bias, init 4-domain h ring.
// Gate order: 0=f, 1=i, 2=g, 3=o.
// WxT: [2048 n][512 k]   WhT: [32 wgl][64 j][512 k]  (j = gate*16 + hc_local)
// h ring: 4 domains x 4 slots x [16 rows][512 cols] bf16 (domain d = batch
// rows 16d..16d+15). Per domain: slot 0 = h_0 = +0.0 (fresh); slots 1..3 =
// 0x8000 poison (bf16 -0.0, never produced: producers cleanse).
// ---------------------------------------------------------------------------
__global__ void lstm_prep(
    const float* __restrict__ Wif, const float* __restrict__ Wii,
    const float* __restrict__ Wig, const float* __restrict__ Wio,
    const float* __restrict__ Whf, const float* __restrict__ Whi,
    const float* __restrict__ Whg, const float* __restrict__ Who,
    const float* __restrict__ bif, const float* __restrict__ bhf,
    const float* __restrict__ bii, const float* __restrict__ bhi,
    const float* __restrict__ big, const float* __restrict__ bhg,
    const float* __restrict__ bio, const float* __restrict__ bho,
    unsigned short* __restrict__ WxT, unsigned short* __restrict__ WhT,
    float* __restrict__ bias, unsigned short* __restrict__ hring)
{
  const long NWX = 2048L * 512, NWH = 32L * 64 * 512;
  const long NR = 4L * 4 * 16 * 512;           // ring: 131072 ushorts
  long total = NWX + NWH + 2048 + NR;
  for (long i = (long)blockIdx.x * blockDim.x + threadIdx.x; i < total;
       i += (long)gridDim.x * blockDim.x) {
    if (i < NWX) {
      int n = (int)(i >> 9), k = (int)(i & 511);
      int g = n >> 9, hc = n & 511;
      const float* W = (g == 0) ? Wif : (g == 1) ? Wii : (g == 2) ? Wig : Wio;
      WxT[i] = f2bf(W[k * 512 + hc]);
    } else if (i < NWX + NWH) {
      long r = i - NWX;
      int wg = (int)(r >> 15); int rest = (int)(r & 32767);
      int j = rest >> 9, k = rest & 511;
      int g = j >> 4, hc = wg * 16 + (j & 15);
      const float* W = (g == 0) ? Whf : (g == 1) ? Whi : (g == 2) ? Whg : Who;
      WhT[r] = f2bf(W[k * 512 + hc]);
    } else if (i < NWX + NWH + 2048) {
      int n = (int)(i - NWX - NWH);
      int g = n >> 9, hc = n & 511;
      const float* bi = (g == 0) ? bif : (g == 1) ? bii : (g == 2) ? big : bio;
      const float* bh = (g == 0) ? bhf : (g == 1) ? bhi : (g == 2) ? bhg : bho;
      bias[n] = bi[hc] + bh[hc];
    } else {
      long r = i - NWX - NWH - 2048;
      long rr = r & 32767;                     // within-domain index
      hring[r] = (rr < 8192) ? (unsigned short)0 : (unsigned short)0x8000u;
    }
  }
}

// ---------------------------------------------------------------------------
// x-projection GEMM: (B*T, 512) @ (512, 2048) + bias -> bf16, written in the
// recurrent kernel's per-lane-packed layout (4-domain, gate-per-wave):
//   dst = ((((t*128 + dd*32 + wgl)*4 + gate)*64 + (chi*16+lcol))*4 + cii
// 128x256 tile (512 mt x 8 ntb): halves A-tile re-reads and pack-VALU per
// MFMA vs the 128x128 version. 4 waves: wm = m-half, wn = n-half (128 wide).
// ---------------------------------------------------------------------------
#define GP 56  // LDS row stride (elems): 112B, 16B-aligned, 2-way banks

__global__ __launch_bounds__(256) void lstm_xproj(
    const float* __restrict__ x, const unsigned short* __restrict__ WxT,
    const float* __restrict__ bias, unsigned short* __restrict__ xp)
{
  __shared__ unsigned short As[128 * GP];   // 14 KB
  __shared__ unsigned short Bs[256 * GP];   // 28 KB
  int bid = blockIdx.x;
  int mt = bid & 511, ntb = bid >> 9;         // 512 m-tiles, 8 n-tiles
  int m0 = mt << 7, n0 = ntb << 8;
  int tid = threadIdx.x, lane = tid & 63, w = tid >> 6;
  int wm = w >> 1, wn = w & 1;
  int l15 = lane & 15, hi4 = lane >> 4;

  f32x4 acc[4][8] = {};
  int srow = tid >> 1, skq = (tid & 1) << 4;  // A: thread = 1 row, 16 k
  const float* xa = x + (size_t)(m0 + srow) * 512 + skq;
  const unsigned short* bsrc = WxT + (size_t)(n0 + tid) * 512;  // B: 1 row/thr
  unsigned short* adst = As + srow * GP + skq;
  unsigned short* bdst = Bs + tid * GP;

  for (int kt = 0; kt < 16; ++kt) {
    f32x4 a0 = *(const f32x4*)(xa + kt * 32);
    f32x4 a1 = *(const f32x4*)(xa + kt * 32 + 4);
    f32x4 a2 = *(const f32x4*)(xa + kt * 32 + 8);
    f32x4 a3 = *(const f32x4*)(xa + kt * 32 + 12);
    u32x4 wv0 = *(const u32x4*)(bsrc + kt * 32);
    u32x4 wv1 = *(const u32x4*)(bsrc + kt * 32 + 8);
    u32x4 wv2 = *(const u32x4*)(bsrc + kt * 32 + 16);
    u32x4 wv3 = *(const u32x4*)(bsrc + kt * 32 + 24);
    u32x4 p0, p1;
    p0[0] = pk2(a0[0], a0[1]); p0[1] = pk2(a0[2], a0[3]);
    p0[2] = pk2(a1[0], a1[1]); p0[3] = pk2(a1[2], a1[3]);
    p1[0] = pk2(a2[0], a2[1]); p1[1] = pk2(a2[2], a2[3]);
    p1[2] = pk2(a3[0], a3[1]); p1[3] = pk2(a3[2], a3[3]);
    *(u32x4*)adst = p0;  *(u32x4*)(adst + 8) = p1;
    *(u32x4*)bdst = wv0;        *(u32x4*)(bdst + 8) = wv1;
    *(u32x4*)(bdst + 16) = wv2; *(u32x4*)(bdst + 24) = wv3;
    __syncthreads();
    short8 af[4], bfr[8];
    #pragma unroll
    for (int mb = 0; mb < 4; ++mb)
      af[mb] = *(const short8*)(As + (wm * 64 + mb * 16 + l15) * GP + hi4 * 8);
    #pragma unroll
    for (int nb = 0; nb < 8; ++nb)
      bfr[nb] = *(const short8*)(Bs + (wn * 128 + nb * 16 + l15) * GP + hi4 * 8);
    #pragma unroll
    for (int mb = 0; mb < 4; ++mb)
      #pragma unroll
      for (int nb = 0; nb < 8; ++nb)
        acc[mb][nb] = mfma16(af[mb], bfr[nb], acc[mb][nb]);
    __syncthreads();
  }
  // epilogue: +bias, bf16, scatter into packed consumer layout
  #pragma unroll
  for (int nb = 0; nb < 8; ++nb) {
    int n = n0 + wn * 128 + nb * 16 + l15;
    int gate = n >> 9, hc = n & 511, wgc = hc >> 4, lcol = hc & 15;
    float bv = bias[n];
    #pragma unroll
    for (int mb = 0; mb < 4; ++mb) {
      int mbase = m0 + wm * 64 + mb * 16 + hi4 * 4;
      #pragma unroll
      for (int i = 0; i < 4; ++i) {
        int m = mbase + i;
        int tt = m & 1023, bb = m >> 10;
        int ddc = bb >> 4, rloc = bb & 15;
        int chi = rloc >> 2, cii = rloc & 3;
        size_t dst = ((((size_t)tt * 128 + ddc * 32 + wgc) * 4 + gate) * 64 +
                      (size_t)(chi * 16 + lcol)) * 4 + cii;
        xp[dst] = f2bf(acc[mb][nb][i] + bv);
      }
    }
  }
}

// ---------------------------------------------------------------------------
// recurrence: 4 independent batch domains x 32 WGs = 128 WGs (R11, verbatim:
// proven 2290 us / step 2.24 us). Sentinel ring, re-poison at top of step,
// early gb issue after B2, own-slice direct to LDS.
// ---------------------------------------------------------------------------
#define AWAIT(N) do { \
  asm volatile("s_waitcnt vmcnt(" #N ")" ::: "memory"); \
  __builtin_amdgcn_sched_barrier(0); } while (0)

#define PLD1(dst, vof, sb) \
  asm volatile("global_load_dwordx4 %0, %1, %2 sc0 sc1" \
               : "=v"(dst) : "v"(vof), "s"(sb))

#define XLD2(dst, a64) \
  asm volatile("global_load_dwordx2 %0, %1, off" : "=v"(dst) : "v"(a64))

__global__ __launch_bounds__(256, 1) void lstm_rec(
    const unsigned short* __restrict__ xp, const unsigned short* __restrict__ WhT,
    unsigned short* __restrict__ hring, float* __restrict__ out)
{
  __shared__ unsigned short hA[8192];    // 16 KB staged h (XOR-swizzled)
  __shared__ float pre[4][16][17];       // 4.4 KB preact exchange

  int wgG = blockIdx.x;
  int dd = wgG >> 5, wgl = wgG & 31;
  int tid = threadIdx.x, lane = tid & 63, g = tid >> 6;   // wave = gate
  int l15 = lane & 15, hi4 = lane >> 4;

  // Wh fragments for this wave's gate: 16 x short8 = 64 VGPR
  short8 bw[16];
  {
    const unsigned short* wsrc =
        WhT + ((size_t)wgl * 64 + g * 16 + l15) * 512 + hi4 * 8;
    #pragma unroll
    for (int kk = 0; kk < 16; ++kk)
      bw[kk] = *(const short8*)(wsrc + kk * 32);
  }

  // poll voffsets + swizzled LDS bytes: 4 granules/thread (16B each)
  unsigned int voff[4], lbyt[4];
  #pragma unroll
  for (int k = 0; k < 4; ++k) {
    int gid = k * 256 + tid;         // granule id 0..1023
    int byt = gid * 16;
    int row = gid >> 6;              // 16 rows, 64 granules/row
    voff[k] = (unsigned)byt;
    lbyt[k] = (unsigned)(byt ^ ((row & 7) << 4));
  }
  // own-column granules (gcol = tid&63): excluded from poll
  int gcol = tid & 63;
  unsigned own = (gcol == wgl * 2 || gcol == wgl * 2 + 1) ? 0xFu : 0x0u;

  // combine coords (tid < 128): row r, 2 consecutive local cols
  const int r = (tid & 127) >> 3;
  const int cq = (tid & 7) * 2;
  float cst[2] = {0.f, 0.f};
  unsigned int vpub = (unsigned)(r * 1024 + (wgl * 16 + cq) * 2);
  unsigned int lown = (unsigned)((r * 1024 + (wgl * 16 + cq) * 2)
                                 ^ ((r & 7) << 4));

  // per-lane 64-bit xp address (this wave's 8B/lane packet for step t)
  unsigned long long xaddr = (unsigned long long)(uintptr_t)(
      xp + ((size_t)(wgG * 4 + g) * 64 + lane) * 4);

  u32x2 pc, pn;
  XLD2(pc, xaddr);

  const size_t dbase = (size_t)dd * 32768;   // domain base (elems)

  u32x4 gb[4];
  // prologue: first-round polls for slot 0 (fresh from prep)
  {
    const unsigned short* hb = hring + dbase;
    #pragma unroll
    for (int k = 0; k < 4; ++k) PLD1(gb[k], voff[k], hb);
  }

  for (int t = 0; t < 1024; ++t) {
    const unsigned short* hb = hring + dbase + ((size_t)(t & 3) << 13);
    // ---- re-poison slot (t-2): issued BEFORE the poll drain ----
    if (t >= 2 && tid < 128) {
      const unsigned short* hp = hring + dbase + ((size_t)((t - 2) & 3) << 13);
      unsigned int pv = 0x80008000u;
      asm volatile("global_store_dword %0, %1, %2 sc0 sc1"
                   :: "v"(vpub), "v"(pv), "s"(hp) : "memory");
    }
    // ---- dirty-mask sentinel poll (first-round loads already in flight) ----
    {
      unsigned m = (t == 0) ? 0xFu : (0xFu & ~own);
      int spins = 0;
      for (;;) {
        AWAIT(0);                    // also drains re-poison, pn, publish acks
        unsigned nm = 0;
        #pragma unroll
        for (int k = 0; k < 4; ++k) {
          if ((m >> k) & 1u) {
            u32x4 v = gb[k];
            bool clean = (v[0] != 0x80008000u) && (v[1] != 0x80008000u) &&
                         (v[2] != 0x80008000u) && (v[3] != 0x80008000u);
            if (clean)
              *(u32x4*)((char*)hA + lbyt[k]) = v;   // stage now
            else
              nm |= (1u << k);
          }
        }
        m = nm;
        if (m == 0u) break;
        if (++spins > (1 << 15)) break;   // bounded: fail visibly, never hang
        #pragma unroll
        for (int k = 0; k < 4; ++k)
          if ((m >> k) & 1u) PLD1(gb[k], voff[k], hb);
      }
    }
    __syncthreads();                // B1: staged h_t complete in LDS

    // ---- acc init from prefetched xp ----
    f32x4 acc;
    #pragma unroll
    for (int i = 0; i < 4; ++i) {
      unsigned int dw = pc[i >> 1];
      unsigned short us = (i & 1) ? (unsigned short)(dw >> 16)
                                  : (unsigned short)(dw & 0xFFFFu);
      acc[i] = bf2f(us);
    }
    if (t < 1023) xaddr += 262144ULL;   // uniform step to next t's packet
    XLD2(pn, xaddr);

    // ---- MFMA: a-frags from swizzled LDS, b-frags from regs ----
    #pragma unroll
    for (int kk = 0; kk < 16; ++kk) {
      int b0 = (l15 * 1024 + kk * 64 + hi4 * 16) ^ ((l15 & 7) << 4);
      short8 a0 = *(const short8*)((const char*)hA + b0);
      acc = mfma16(a0, bw[kk], acc);
    }
    // ---- preact dump ----
    #pragma unroll
    for (int i = 0; i < 4; ++i)
      pre[g][hi4 * 4 + i][l15] = acc[i];
    __syncthreads();                // B2

    // ---- early issue: first-round polls for slot t+1 (non-own granules) ----
    if (t < 1023) {
      const unsigned short* hbn =
          hring + dbase + ((size_t)((t + 1) & 3) << 13);
      #pragma unroll
      for (int k = 0; k < 4; ++k)
        if (!((own >> k) & 1u)) PLD1(gb[k], voff[k], hbn);
    }

    // ---- combine (tid < 128): row r, local cols cq..cq+1 ----
    if (tid < 128) {
      float hv[2];
      #pragma unroll
      for (int i = 0; i < 2; ++i) {
        float fg = sigm(pre[0][r][cq + i]);
        float ig = sigm(pre[1][r][cq + i]);
        float gg = tanh_(pre[2][r][cq + i]);
        float og = sigm(pre[3][r][cq + i]);
        float c = fg * cst[i] + ig * gg;
        cst[i] = c;
        hv[i] = og * tanh_(c);
      }
      if (t < 1023) {
        unsigned int u0 = f2bf(hv[0]), u1 = f2bf(hv[1]);
        if (u0 == 0x8000u) u0 = 0;    // cleanse -0.0 (poison)
        if (u1 == 0x8000u) u1 = 0;
        unsigned int pk = u0 | (u1 << 16);
        const unsigned short* hbn =
            hring + dbase + ((size_t)((t + 1) & 3) << 13);
        asm volatile("global_store_dword %0, %1, %2 sc0 sc1"
                     :: "v"(vpub), "v"(pk), "s"(hbn) : "memory");
        // own slice direct to LDS for next step (skips the global RT)
        *(unsigned int*)((char*)hA + lown) = pk;
      } else {
        int b = dd * 16 + r, col = wgl * 16 + cq;
        out[(size_t)b * 512 + col] = hv[0];
        out[(size_t)b * 512 + col + 1] = hv[1];
        out[32768 + (size_t)b * 512 + col] = cst[0];
        out[32768 + (size_t)b * 512 + col + 1] = cst[1];
      }
    }
    pc = pn;
  }
}

// ---------------------------------------------------------------------------
extern "C" void kernel_launch(void* const* d_in, const int* in_sizes, int n_in,
                              void* d_out, int out_size, void* d_ws, size_t ws_size,
                              hipStream_t stream) {
  const float* x   = (const float*)d_in[0];
  const float* Wii = (const float*)d_in[1];
  const float* Whi = (const float*)d_in[2];
  const float* Wif = (const float*)d_in[3];
  const float* Whf = (const float*)d_in[4];
  const float* Wig = (const float*)d_in[5];
  const float* Whg = (const float*)d_in[6];
  const float* Wio = (const float*)d_in[7];
  const float* Who = (const float*)d_in[8];
  const float* bii = (const float*)d_in[9];
  const float* bhi = (const float*)d_in[10];
  const float* bif = (const float*)d_in[11];
  const float* bhf = (const float*)d_in[12];
  const float* big = (const float*)d_in[13];
  const float* bhg = (const float*)d_in[14];
  const float* bio = (const float*)d_in[15];
  const float* bho = (const float*)d_in[16];

  char* ws = (char*)d_ws;
  size_t off = 0;
  auto alloc = [&](size_t bytes) {
    size_t p = off; off = (off + bytes + 255) & ~(size_t)255; return p;
  };
  unsigned short* WxT  = (unsigned short*)(ws + alloc(2048UL * 512 * 2));
  unsigned short* WhT  = (unsigned short*)(ws + alloc(32UL * 64 * 512 * 2));
  float*          bias = (float*)        (ws + alloc(2048UL * 4));
  unsigned short* hring= (unsigned short*)(ws + alloc(4UL * 4 * 16 * 512 * 2));
  unsigned short* xpb  = (unsigned short*)(ws + alloc(1024UL * 64 * 2048 * 2));
  if (off > ws_size) return;  // insufficient workspace -> fail visibly

  lstm_prep<<<2048, 256, 0, stream>>>(Wif, Wii, Wig, Wio, Whf, Whi, Whg, Who,
                                      bif, bhf, bii, bhi, big, bhg, bio, bho,
                                      WxT, WhT, bias, hring);
  lstm_xproj<<<4096, 256, 0, stream>>>(x, WxT, bias, xpb);
  lstm_rec<<<128, 256, 0, stream>>>(xpb, WhT, hring, (float*)d_out);
}